// Round 8
// baseline (1322.047 us; speedup 1.0000x reference)
//
#include <hip/hip_runtime.h>
#include <float.h>
#include <math.h>

// DGCNN control-points pipeline, fp32 compute, f16-MFMA for the layer-5 GEMM.
//
// Edge conv decomposition: y[b,o,n,k] = W·[nbr-ctr; ctr]
//   = v[b, idx(n,k), o] + u[b,n,o]   with v = Wd·x, u = (Wc-Wd)·x
// BN is batch-stats. Single gather pass records per-(b,n,o) ymax/ymin and
// accumulates per-channel sum/sumsq; BN+lrelu+k-max applied elementwise
// afterwards (monotone-affine trick), so gathers happen exactly once.
// knn: 8-row blocks (512 thr) stream X once per 8 queries (R7 profile: knn is
// L2-BW bound re-streaming X per 4 rows); distances in 64 KB LDS; per-wave
// register-resident top-20 (named regs + chunk-min caches + dual butterfly,
// exact lexicographic (dist,idx) = lax.top_k semantics).
// Layer-5 (2048x963x8192) runs on matrix cores in f16 (fp32 accum), with the
// BN-stat/max reduction fused into the epilogue via atomics.

#define NPTS 2048
#define BATCH 4
#define KNN 20
#define CH_H 963
#define KPAD 992              // 963 padded to 31*32
#define HSTRIDE (CH_H*NPTS)   // per-batch element stride of concat buffer H

typedef _Float16 half8 __attribute__((ext_vector_type(8)));
typedef float f32x4 __attribute__((ext_vector_type(4)));

// order-preserving float<->uint for atomicMax/Min
__device__ __forceinline__ unsigned fenc(float x){
  unsigned u = __float_as_uint(x);
  return (u & 0x80000000u) ? ~u : (u | 0x80000000u);
}
__device__ __forceinline__ float fdec(unsigned u){
  u = (u & 0x80000000u) ? (u ^ 0x80000000u) : ~u;
  return __uint_as_float(u);
}

// ---------------- copy input x (B,3,N) -> H rows [0,3) ----------------
__global__ void k_convert(const float* __restrict__ x, float* __restrict__ H){
  int i = blockIdx.x*256 + threadIdx.x;
  if (i >= BATCH*3*NPTS) return;
  int b = i / (3*NPTS); int r = i % (3*NPTS);
  H[(size_t)b*HSTRIDE + r] = x[i];
}

// ---------------- per-point squared norms (+ zero SUM/SUMSQ for this layer) ----------------
__global__ void k_norms(const float* __restrict__ X, int C, float* __restrict__ X2,
                        float* __restrict__ SUMZ){
  int i = blockIdx.x*256 + threadIdx.x;     // b*2048+n
  if (i < 1024) SUMZ[i] = 0.f;              // SUM[512] ++ SUMSQ[512] contiguous
  int b = i >> 11, n = i & 2047;
  const float* Xb = X + (size_t)b*HSTRIDE + n;
  float s = 0.f;
  for (int c=0;c<C;++c){ float v = Xb[(size_t)c*NPTS]; s = fmaf(v,v,s); }
  X2[i] = s;
}

// ---------------- knn ----------------
// 32 register slots per lane: slot (ch,cp) <-> candidate m = ch*256 + (lane<<2) + cp
#define KNN_CH(OPC) OPC(0) OPC(1) OPC(2) OPC(3) OPC(4) OPC(5) OPC(6) OPC(7)
#define DECL_CH(ch) float d##ch##_0,d##ch##_1,d##ch##_2,d##ch##_3;
#define LOAD_CH(ch) { float4 f = *(const float4*)(dlw + (ch)*256 + base); \
  d##ch##_0=f.x; d##ch##_1=f.y; d##ch##_2=f.z; d##ch##_3=f.w; }
#define DECL_G(ch) float gv##ch; int gm##ch;
// strict < in ascending slot order -> smallest idx among exact ties
#define MKCH(ch) { gv##ch = d##ch##_0; gm##ch = (ch)*256 + base; \
  if (d##ch##_1 < gv##ch){ gv##ch = d##ch##_1; gm##ch = (ch)*256 + base + 1; } \
  if (d##ch##_2 < gv##ch){ gv##ch = d##ch##_2; gm##ch = (ch)*256 + base + 2; } \
  if (d##ch##_3 < gv##ch){ gv##ch = d##ch##_3; gm##ch = (ch)*256 + base + 3; } }
#define REMCASE(ch) case ch: { \
  if (own){ if (cp==0) d##ch##_0 = FLT_MAX; else if (cp==1) d##ch##_1 = FLT_MAX; \
            else if (cp==2) d##ch##_2 = FLT_MAX; else d##ch##_3 = FLT_MAX; } \
  MKCH(ch) } break;

// 8 query rows per block, 512 threads. Distance phase: thread (rh=tid>>8,
// mg=tid&255) computes rows rh*4..rh*4+3 vs candidates mg*8..mg*8+7. The
// query float4 X[c][n0+rh*4..] is inside the candidate row being streamed ->
// L1 broadcast hit, no LDS staging needed. dl = 64 KB (the per-WG limit).
__global__ __launch_bounds__(512,4) void k_knn(const float* __restrict__ X, int C,
        const float* __restrict__ X2, int* __restrict__ IDX)
{
  __shared__ __align__(16) float dl[8][NPTS];     // 64 KB distances
  int bi = blockIdx.x;
  int b  = bi >> 8;                 // 256 blocks per batch (2048/8 rows)
  int n0 = (bi & 255) * 8;
  int tid = threadIdx.x;
  int rh = tid >> 8;                // row-half: rows rh*4 .. rh*4+3
  int mg = tid & 255;
  int m0 = mg * 8;
  const float* Xb = X + (size_t)b*HSTRIDE;
  float acc[4][8];
  #pragma unroll
  for (int r=0;r<4;++r)
    #pragma unroll
    for (int j=0;j<8;++j) acc[r][j]=0.f;
  for (int c=0;c<C;++c){
    const float* rowc = Xb + (size_t)c*NPTS;
    const float4 xq = *(const float4*)(rowc + n0 + rh*4);   // L1 broadcast
    const float4* p = (const float4*)(rowc + m0);
    float4 v0 = p[0], v1 = p[1];
    float mv[8] = {v0.x,v0.y,v0.z,v0.w,v1.x,v1.y,v1.z,v1.w};
    float xr[4] = {xq.x, xq.y, xq.z, xq.w};
    #pragma unroll
    for (int r=0;r<4;++r){
      #pragma unroll
      for (int j=0;j<8;++j) acc[r][j] = fmaf(xr[r], mv[j], acc[r][j]);
    }
  }
  float x2m[8];
  #pragma unroll
  for (int j=0;j<8;++j) x2m[j] = X2[(b<<11) + m0 + j];
  #pragma unroll
  for (int r=0;r<4;++r){
    float x2r = X2[(b<<11) + n0 + rh*4 + r];
    #pragma unroll
    for (int j=0;j<8;++j) dl[rh*4+r][m0+j] = x2r + x2m[j] - 2.f*acc[r][j];
  }
  __syncthreads();
  // ---- selection: wave w owns row n0+w (8 waves) ----
  int w = tid >> 6, lane = tid & 63;
  int base = lane << 2;
  const float* dlw = dl[w];
  KNN_CH(DECL_CH)
  KNN_CH(LOAD_CH)
  KNN_CH(DECL_G)
  KNN_CH(MKCH)
  int* op = IDX + ((size_t)(b<<11)+n0+w)*KNN;
  for (int it=0; it<KNN; ++it){
    float v = fminf(fminf(fminf(gv0,gv1),fminf(gv2,gv3)),
                    fminf(fminf(gv4,gv5),fminf(gv6,gv7)));
    #pragma unroll
    for (int s=1; s<64; s<<=1) v = fminf(v, __shfl_xor(v, s));
    int mc = 0x7fffffff;
    mc = (gv7==v) ? gm7 : mc;
    mc = (gv6==v) ? gm6 : mc;
    mc = (gv5==v) ? gm5 : mc;
    mc = (gv4==v) ? gm4 : mc;
    mc = (gv3==v) ? gm3 : mc;
    mc = (gv2==v) ? gm2 : mc;
    mc = (gv1==v) ? gm1 : mc;
    mc = (gv0==v) ? gm0 : mc;
    int m = mc;
    #pragma unroll
    for (int s=1; s<64; s<<=1) m = min(m, __shfl_xor(m, s));
    if (lane==0) op[it] = m;
    int sm = __builtin_amdgcn_readfirstlane(m);
    bool own = (lane == ((sm>>2)&63));
    int cp = sm & 3;
    switch (sm >> 8){ KNN_CH(REMCASE) }
  }
}

// ---------------- v = Wd*x, u = (Wc-Wd)*x : 128x64 tile, 8x4/thread ----------------
__global__ __launch_bounds__(256) void k_vu(const float* __restrict__ X,
        const float* __restrict__ W, int C, int O,
        float* __restrict__ V, float* __restrict__ U)
{
  __shared__ float Xs[8][128];
  __shared__ float Wdv[8][64];
  __shared__ float Wuv[8][64];
  int b = blockIdx.z, n0 = blockIdx.x*128, o0 = blockIdx.y*64;
  int tid = threadIdx.x;
  int tj = tid & 15, ti = tid >> 4;   // tj -> o (4 each), ti -> n (8 each)
  float4 aV[8], aU[8];
  #pragma unroll
  for (int i=0;i<8;++i){ aV[i]=make_float4(0,0,0,0); aU[i]=make_float4(0,0,0,0); }
  const float* Xb = X + (size_t)b*HSTRIDE;
  for (int c0=0;c0<C;c0+=8){
    {
      int cc = tid >> 5, nn = (tid & 31) * 4; int c = c0 + cc;
      float4 v = (c<C) ? *(const float4*)(Xb + (size_t)c*NPTS + n0 + nn)
                       : make_float4(0,0,0,0);
      *(float4*)&Xs[cc][nn] = v;
    }
    for (int l=tid;l<512;l+=256){
      int oo=l>>3, cc=l&7, c=c0+cc;
      float wd=0.f, wu=0.f;
      if (c<C){
        const float* wr = W + (size_t)(o0+oo)*(2*C);
        wd = wr[c]; wu = wr[C+c] - wd;
      }
      Wdv[cc][oo]=wd; Wuv[cc][oo]=wu;
    }
    __syncthreads();
    #pragma unroll
    for (int cc=0;cc<8;++cc){
      float4 x0 = *(float4*)&Xs[cc][ti*8];
      float4 x1 = *(float4*)&Xs[cc][ti*8+4];
      float4 wd = *(float4*)&Wdv[cc][tj*4];
      float4 wu = *(float4*)&Wuv[cc][tj*4];
      float xs[8] = {x0.x,x0.y,x0.z,x0.w,x1.x,x1.y,x1.z,x1.w};
      #pragma unroll
      for (int i=0;i<8;++i){
        aV[i].x = fmaf(xs[i], wd.x, aV[i].x);
        aV[i].y = fmaf(xs[i], wd.y, aV[i].y);
        aV[i].z = fmaf(xs[i], wd.z, aV[i].z);
        aV[i].w = fmaf(xs[i], wd.w, aV[i].w);
        aU[i].x = fmaf(xs[i], wu.x, aU[i].x);
        aU[i].y = fmaf(xs[i], wu.y, aU[i].y);
        aU[i].z = fmaf(xs[i], wu.z, aU[i].z);
        aU[i].w = fmaf(xs[i], wu.w, aU[i].w);
      }
    }
    __syncthreads();
  }
  #pragma unroll
  for (int i=0;i<8;++i){
    int n = n0 + ti*8 + i;
    size_t basep = ((size_t)b*NPTS + n)*O + o0 + tj*4;
    *(float4*)(V+basep) = aV[i];
    *(float4*)(U+basep) = aU[i];
  }
}

// ---------------- single gather pass: ymax/ymin per (b,n,o) + channel sum/sumsq ----------------
__global__ __launch_bounds__(256) void k_gather(const float* __restrict__ V, const float* __restrict__ U,
        const int* __restrict__ IDX, int O,
        float* __restrict__ YMX, float* __restrict__ YMN,
        float* __restrict__ SUM, float* __restrict__ SUMSQ)
{
  const int NT = 8;
  __shared__ int sidx[NT*KNN];
  int bi = blockIdx.x;                 // 4*256 blocks
  int b  = bi >> 8;
  int n0 = (bi & 255) * NT;
  int tid = threadIdx.x;
  for (int l = tid; l < NT*KNN; l += 256)
    sidx[l] = IDX[((size_t)(b<<11)+n0)*KNN + l];
  __syncthreads();
  int othr  = (O < 256) ? O : 256;     // power of 2
  int o0    = tid & (othr-1);
  int ns    = tid / othr;
  int nstep = 256 / othr;
  for (int o = o0; o < O; o += othr){
    float s = 0.f, q = 0.f;
    for (int nn = ns; nn < NT; nn += nstep){
      int n = n0 + nn;
      size_t ub = ((size_t)(b<<11)+n)*O + o;
      float u = U[ub];
      float mx = -FLT_MAX, mn = FLT_MAX;
      #pragma unroll
      for (int k=0;k<KNN;++k){
        int m = sidx[nn*KNN+k];
        float y = V[((size_t)(b<<11)+m)*O + o] + u;
        mx = fmaxf(mx,y); mn = fminf(mn,y);
        s += y; q = fmaf(y,y,q);
      }
      YMX[ub] = mx; YMN[ub] = mn;
    }
    atomicAdd(&SUM[o], s); atomicAdd(&SUMSQ[o], q);
  }
}

__global__ void k_finalize(const float* __restrict__ SUM, const float* __restrict__ SUMSQ,
        const float* __restrict__ g, const float* __restrict__ bt,
        int O, float invM, float* __restrict__ SC, float* __restrict__ SH){
  int o = blockIdx.x*256 + threadIdx.x;
  if (o>=O) return;
  float m = SUM[o]*invM;
  float var = SUMSQ[o]*invM - m*m;
  float sc = g[o] * rsqrtf(var + 1e-5f);
  SC[o]=sc; SH[o] = bt[o] - m*sc;
}

// ---------------- apply BN + lrelu to recorded extrema; transpose (b,n,o)->(b,o,n) ----------------
__global__ __launch_bounds__(256) void k_apply(const float* __restrict__ YMX, const float* __restrict__ YMN,
        const float* __restrict__ SC, const float* __restrict__ SH,
        int O, float* __restrict__ OUT)
{
  __shared__ float t[64][65];
  int b = blockIdx.z;
  int o0 = blockIdx.y*64, n0 = blockIdx.x*64;
  int tid = threadIdx.x;
  int lo = tid & 63, ln = tid >> 6;
  float sc = SC[o0+lo], sh = SH[o0+lo];
  for (int nn = ln; nn < 64; nn += 4){
    size_t idx = ((size_t)(b<<11)+n0+nn)*O + o0 + lo;
    float v = (sc >= 0.f) ? YMX[idx] : YMN[idx];
    float y = fmaf(sc, v, sh);
    y = (y > 0.f) ? y : 0.2f*y;
    t[lo][nn] = y;
  }
  __syncthreads();
  for (int oo = ln; oo < 64; oo += 4){
    OUT[(size_t)b*HSTRIDE + (size_t)(o0+oo)*NPTS + n0 + lo] = t[oo][lo];
  }
}

// ---------------- transpose H (b,c,n) fp32 -> Hf16 (b,n,KPAD) f16, zero-pad c>=963 ----------------
__global__ __launch_bounds__(256) void k_h2f16(const float* __restrict__ H, _Float16* __restrict__ Hf){
  __shared__ float t[64][65];
  int b = blockIdx.z;
  int n0 = blockIdx.x*64, c0 = blockIdx.y*64;
  int tid = threadIdx.x; int l = tid & 63, m = tid >> 6;
  for (int cc = m; cc < 64; cc += 4){
    int c = c0 + cc;
    t[cc][l] = (c < CH_H) ? H[(size_t)b*HSTRIDE + (size_t)c*NPTS + n0 + l] : 0.f;
  }
  __syncthreads();
  for (int nn = m; nn < 64; nn += 4){
    int c = c0 + l;
    if (c < KPAD)
      Hf[((size_t)(b<<11)+n0+nn)*KPAD + c] = (_Float16)t[l][nn];
  }
}

// ---------------- w5 -> f16 (+ zero l5 reduction buffers) ----------------
__global__ void k_w5f16(const float* __restrict__ w5, _Float16* __restrict__ Wf,
                        unsigned* __restrict__ z){
  int i = blockIdx.x*256 + threadIdx.x;
  if (i < 12288) z[i] = 0u;                 // SUM5,SUMSQ5,MAXB
  else if (i < 20480) z[i] = 0xFFFFFFFFu;   // MINB
  if (i >= 2048*KPAD) return;
  int o = i / KPAD, c = i - o*KPAD;
  Wf[i] = (c < CH_H) ? (_Float16)w5[(size_t)o*CH_H + c] : (_Float16)0.f;
}

// ---------------- layer-5 GEMM on MFMA, fused BN-stat/max epilogue ----------------
__global__ __launch_bounds__(256) void k_l5mfma(const _Float16* __restrict__ Wf,
        const _Float16* __restrict__ Hf,
        float* __restrict__ SUM5, float* __restrict__ SUMSQ5,
        unsigned* __restrict__ MAXB, unsigned* __restrict__ MINB)
{
  __shared__ half8 As[128][4];   // [o_row][k-chunk of 8]
  __shared__ half8 Bs[128][4];   // [n_row][k-chunk of 8]
  int b  = blockIdx.z;
  int n0 = blockIdx.x*128, o0 = blockIdx.y*128;
  int tid = threadIdx.x;
  int w = tid>>6, lane = tid&63;
  int wm = w>>1, wn = w&1;          // wave grid 2x2
  int quad = lane>>4, col = lane&15;
  f32x4 acc[4][4];
  #pragma unroll
  for (int i=0;i<4;++i)
    #pragma unroll
    for (int j=0;j<4;++j) acc[i][j] = (f32x4){0.f,0.f,0.f,0.f};

  for (int k0=0; k0<KPAD; k0+=32){
    #pragma unroll
    for (int h=0; h<2; ++h){
      int cid = tid + h*256;
      int row = cid>>2, kc = cid&3;
      As[row][kc] = *(const half8*)(Wf + (size_t)(o0+row)*KPAD + k0 + kc*8);
      Bs[row][kc] = *(const half8*)(Hf + ((size_t)(b<<11)+n0+row)*KPAD + k0 + kc*8);
    }
    __syncthreads();
    half8 af[4], bf[4];
    #pragma unroll
    for (int mt=0;mt<4;++mt) af[mt] = As[wm*64 + mt*16 + col][quad];
    #pragma unroll
    for (int nt=0;nt<4;++nt) bf[nt] = Bs[wn*64 + nt*16 + col][quad];
    #pragma unroll
    for (int mt=0;mt<4;++mt)
      #pragma unroll
      for (int nt=0;nt<4;++nt)
        acc[mt][nt] = __builtin_amdgcn_mfma_f32_16x16x32_f16(af[mt], bf[nt], acc[mt][nt], 0, 0, 0);
    __syncthreads();
  }
  // epilogue: C/D layout col(n)=lane&15, row(o)=quad*4+reg
  #pragma unroll
  for (int mt=0;mt<4;++mt){
    #pragma unroll
    for (int r=0;r<4;++r){
      float s=0.f, q=0.f, mx=-FLT_MAX, mn=FLT_MAX;
      #pragma unroll
      for (int nt=0;nt<4;++nt){
        float y = acc[mt][nt][r];
        s += y; q = fmaf(y,y,q);
        mx = fmaxf(mx,y); mn = fminf(mn,y);
      }
      #pragma unroll
      for (int d=8; d; d>>=1){
        s += __shfl_down(s,(unsigned)d,16);
        q += __shfl_down(q,(unsigned)d,16);
        mx = fmaxf(mx,__shfl_down(mx,(unsigned)d,16));
        mn = fminf(mn,__shfl_down(mn,(unsigned)d,16));
      }
      if (col==0){
        int o = o0 + wm*64 + mt*16 + quad*4 + r;
        atomicAdd(&SUM5[o], s);
        atomicAdd(&SUMSQ5[o], q);
        atomicMax(&MAXB[(b<<11)+o], fenc(mx));
        atomicMin(&MINB[(b<<11)+o], fenc(mn));
      }
    }
  }
}

// ---------------- layer-5 finalize: BN + leaky_relu + max over n -> P (B,2048) ----------------
__global__ void k_l5_final(const float* __restrict__ SUM5, const float* __restrict__ SUMSQ5,
        const unsigned* __restrict__ MAXB, const unsigned* __restrict__ MINB,
        const float* __restrict__ g5, const float* __restrict__ b5, float* __restrict__ P)
{
  int o = blockIdx.x*256 + threadIdx.x;
  if (o>=2048) return;
  float m = SUM5[o]*(1.f/8192.f);
  float var = SUMSQ5[o]*(1.f/8192.f) - m*m;
  float sc = g5[o] * rsqrtf(var + 1e-5f);
  float sh = b5[o] - m*sc;
  for (int b=0;b<4;++b){
    float mx = fdec(MAXB[b*2048+o]);
    float mn = fdec(MINB[b*2048+o]);
    float v = (sc >= 0.f) ? fmaf(sc,mx,sh) : fmaf(sc,mn,sh);
    v = (v > 0.f) ? v : 0.2f*v;
    P[b*2048 + o] = v;
  }
}

// ---------------- small FC: Y(B,O) = W(O,Cin)*Z(B,Cin) + bias, one wave per o ----------------
__global__ __launch_bounds__(256) void k_fc(const float* __restrict__ W, const float* __restrict__ bias,
        const float* __restrict__ Z, int Cin, int O, float* __restrict__ Y)
{
  int o = blockIdx.x*4 + (threadIdx.x>>6);
  int lane = threadIdx.x & 63;
  if (o >= O) return;
  const float* wr = W + (size_t)o*Cin;
  float a0=0.f,a1=0.f,a2=0.f,a3=0.f;
  for (int c=lane;c<Cin;c+=64){
    float w = wr[c];
    a0 = fmaf(w, Z[c],        a0);
    a1 = fmaf(w, Z[Cin+c],    a1);
    a2 = fmaf(w, Z[2*Cin+c],  a2);
    a3 = fmaf(w, Z[3*Cin+c],  a3);
  }
  #pragma unroll
  for (int s=32;s;s>>=1){
    a0 += __shfl_down(a0,(unsigned)s); a1 += __shfl_down(a1,(unsigned)s);
    a2 += __shfl_down(a2,(unsigned)s); a3 += __shfl_down(a3,(unsigned)s);
  }
  if (lane==0){
    float bb = bias[o];
    Y[o]=a0+bb; Y[O+o]=a1+bb; Y[2*O+o]=a2+bb; Y[3*O+o]=a3+bb;
  }
}

// ---------------- BN over batch (4 samples) + relu ----------------
__global__ void k_bn4(const float* __restrict__ Y, const float* __restrict__ g, const float* __restrict__ bt,
                      int O, float* __restrict__ Z, int zstride, int zoff)
{
  int o = blockIdx.x*256 + threadIdx.x;
  if (o>=O) return;
  float v0=Y[o], v1=Y[O+o], v2=Y[2*O+o], v3=Y[3*O+o];
  float m = 0.25f*(v0+v1+v2+v3);
  float d0=v0-m, d1=v1-m, d2=v2-m, d3=v3-m;
  float var = 0.25f*(d0*d0+d1*d1+d2*d2+d3*d3);
  float sc = g[o] * rsqrtf(var + 1e-5f);
  float sh = bt[o] - m*sc;
  Z[0*zstride+zoff+o] = fmaxf(fmaf(sc,v0,sh), 0.f);
  Z[1*zstride+zoff+o] = fmaxf(fmaf(sc,v1,sh), 0.f);
  Z[2*zstride+zoff+o] = fmaxf(fmaf(sc,v2,sh), 0.f);
  Z[3*zstride+zoff+o] = fmaxf(fmaf(sc,v3,sh), 0.f);
}

__global__ void k_copy_p(const float* __restrict__ P, float* __restrict__ Z){
  int i = blockIdx.x*256 + threadIdx.x;   // < 4*2048
  int b = i>>11, o = i&2047;
  Z[b*4096 + 2048 + o] = P[i];
}

// ---------------- final: y8 = w8*z7 + wb8, tanh, fp32 out (4,400) ----------------
__global__ __launch_bounds__(256) void k_final(const float* __restrict__ W8, const float* __restrict__ wb8,
        const float* __restrict__ Z7, float* __restrict__ out)
{
  int o = blockIdx.x*4 + (threadIdx.x>>6);
  int lane = threadIdx.x & 63;
  if (o >= 400) return;
  const float* wr = W8 + (size_t)o*4096;
  float a0=0.f,a1=0.f,a2=0.f,a3=0.f;
  for (int c=lane;c<4096;c+=64){
    float w = wr[c];
    a0 = fmaf(w, Z7[c],        a0);
    a1 = fmaf(w, Z7[4096+c],   a1);
    a2 = fmaf(w, Z7[2*4096+c], a2);
    a3 = fmaf(w, Z7[3*4096+c], a3);
  }
  #pragma unroll
  for (int s=32;s;s>>=1){
    a0 += __shfl_down(a0,(unsigned)s); a1 += __shfl_down(a1,(unsigned)s);
    a2 += __shfl_down(a2,(unsigned)s); a3 += __shfl_down(a3,(unsigned)s);
  }
  if (lane==0){
    float bb = wb8[o];
    out[0*400+o] = tanhf(a0+bb);
    out[1*400+o] = tanhf(a1+bb);
    out[2*400+o] = tanhf(a2+bb);
    out[3*400+o] = tanhf(a3+bb);
  }
}

extern "C" void kernel_launch(void* const* d_in, const int* in_sizes, int n_in,
                              void* d_out, int out_size, void* d_ws, size_t ws_size,
                              hipStream_t stream)
{
  const float* x   = (const float*)d_in[0];
  const float* w_e[4]  = {(const float*)d_in[1], (const float*)d_in[4], (const float*)d_in[7], (const float*)d_in[10]};
  const float* g_e[4]  = {(const float*)d_in[2], (const float*)d_in[5], (const float*)d_in[8], (const float*)d_in[11]};
  const float* b_e[4]  = {(const float*)d_in[3], (const float*)d_in[6], (const float*)d_in[9], (const float*)d_in[12]};
  const float* w5  = (const float*)d_in[13];
  const float* g5  = (const float*)d_in[14];
  const float* b5  = (const float*)d_in[15];
  const float* w6  = (const float*)d_in[16];
  const float* wb6 = (const float*)d_in[17];
  const float* g6  = (const float*)d_in[18];
  const float* b6  = (const float*)d_in[19];
  const float* w7  = (const float*)d_in[20];
  const float* wb7 = (const float*)d_in[21];
  const float* g7  = (const float*)d_in[22];
  const float* b7  = (const float*)d_in[23];
  const float* w8  = (const float*)d_in[24];
  const float* wb8 = (const float*)d_in[25];

  float* WS = (float*)d_ws;
  float* H    = WS;                          // 7,888,896
  float* V    = WS + 7888896;                // 4,194,304
  float* U    = V  + 4194304;                // 4,194,304
  float* YMX  = U  + 4194304;                // 4,194,304
  float* YMN  = YMX+ 4194304;                // 4,194,304
  int*   IDX  = (int*)(YMN + 4194304);       //   163,840 ints
  float* X2   = (float*)(IDX + 163840);      //     8,192
  float* SUM  = X2 + 8192;                   //       512
  float* SUMSQ= SUM + 512;                   //       512
  float* SC   = SUMSQ + 512;                 //       512
  float* SH   = SC + 512;                    //       512
  float* SUM5 = SH + 512;                    //     2,048
  float* SUMSQ5 = SUM5 + 2048;               //     2,048
  unsigned* MAXB = (unsigned*)(SUMSQ5 + 2048); //   8,192
  unsigned* MINB = MAXB + 8192;              //     8,192
  float* P    = (float*)(MINB + 8192);       //     8,192
  float* Y6   = P + 8192;                    //     8,192
  float* Z    = Y6 + 8192;                   //    16,384
  float* Y7   = Z + 16384;                   //    16,384
  float* Z7   = Y7 + 16384;                  //    16,384
  // f16 operands for layer-5 MFMA alias the dead V/U buffers:
  _Float16* Hf = (_Float16*)V;               // 4*2048*992 halfs = 16.25 MB <= V (16.78 MB)
  _Float16* Wf = (_Float16*)U;               // 2048*992 halfs = 4.06 MB   <= U

  k_convert<<<96,256,0,stream>>>(x, H);

  const int Cin_[4]  = {3,64,128,256};
  const int O_[4]    = {64,128,256,512};
  const int ioff_[4] = {0,3,67,195};
  const int ooff_[4] = {3,67,195,451};

  for (int l=0;l<4;++l){
    const float* Xl = H + (size_t)ioff_[l]*NPTS;
    int C = Cin_[l], O = O_[l];
    k_norms<<<32,256,0,stream>>>(Xl, C, X2, SUM);
    k_knn<<<1024,512,0,stream>>>(Xl, C, X2, IDX);
    dim3 gvu(16, O/64, 4);
    k_vu<<<gvu,256,0,stream>>>(Xl, w_e[l], C, O, V, U);
    k_gather<<<1024,256,0,stream>>>(V, U, IDX, O, YMX, YMN, SUM, SUMSQ);
    k_finalize<<<2,256,0,stream>>>(SUM, SUMSQ, g_e[l], b_e[l], O, 1.f/163840.f, SC, SH);
    dim3 gap(32, O/64, 4);
    k_apply<<<gap,256,0,stream>>>(YMX, YMN, SC, SH, O, H + (size_t)ooff_[l]*NPTS);
  }

  // ---- layer 5 on MFMA ----
  dim3 gtr(32,16,4);
  k_h2f16<<<gtr,256,0,stream>>>(H, Hf);
  k_w5f16<<<(2048*KPAD+255)/256,256,0,stream>>>(w5, Wf, (unsigned*)SUM5);
  dim3 g5g(16,16,4);
  k_l5mfma<<<g5g,256,0,stream>>>(Wf, Hf, SUM5, SUMSQ5, MAXB, MINB);
  k_l5_final<<<8,256,0,stream>>>(SUM5, SUMSQ5, MAXB, MINB, g5, b5, P);

  k_fc<<<512,256,0,stream>>>(w6, wb6, P, 2048, 2048, Y6);
  k_bn4<<<8,256,0,stream>>>(Y6, g6, b6, 2048, Z, 4096, 0);
  k_copy_p<<<32,256,0,stream>>>(P, Z);
  k_fc<<<1024,256,0,stream>>>(w7, wb7, Z, 4096, 4096, Y7);
  k_bn4<<<16,256,0,stream>>>(Y7, g7, b7, 4096, Z7, 4096, 0);
  k_final<<<100,256,0,stream>>>(w8, wb8, Z7, (float*)d_out);
}

// Round 9
// 1192.922 us; speedup vs baseline: 1.1082x; 1.1082x over previous
//
#include <hip/hip_runtime.h>
#include <float.h>
#include <math.h>

// DGCNN control-points pipeline, fp32 compute; MFMA (f16 hi/lo split) for the
// knn Gram matrix and f16-MFMA for the layer-5 GEMM.
//
// Edge conv decomposition: y[b,o,n,k] = W·[nbr-ctr; ctr]
//   = v[b, idx(n,k), o] + u[b,n,o]   with v = Wd·x, u = (Wc-Wd)·x
// BN is batch-stats. Single gather pass records per-(b,n,o) ymax/ymin and
// accumulates per-channel sum/sumsq; BN+lrelu+k-max applied elementwise.
// knn: G = X^T X via mfma_f32_16x16x32_f16 with x = hi+lo f16 split
// (3 cross terms, fp32 accumulate -> ~2^-22 relative error, fp32-class);
// d = x2[n]+x2[m]-2G; per-wave register top-20 (named regs + chunk-min
// caches + dual butterfly, exact lexicographic (dist,idx) = lax.top_k).
// Layer-5 (2048x963x8192) on matrix cores, BN-stat/max fused via atomics.

#define NPTS 2048
#define BATCH 4
#define KNN 20
#define CH_H 963
#define KPAD 992              // 963 padded to 31*32
#define HSTRIDE (CH_H*NPTS)   // per-batch element stride of concat buffer H

typedef _Float16 half8 __attribute__((ext_vector_type(8)));
typedef float f32x4 __attribute__((ext_vector_type(4)));

// order-preserving float<->uint for atomicMax/Min
__device__ __forceinline__ unsigned fenc(float x){
  unsigned u = __float_as_uint(x);
  return (u & 0x80000000u) ? ~u : (u | 0x80000000u);
}
__device__ __forceinline__ float fdec(unsigned u){
  u = (u & 0x80000000u) ? (u ^ 0x80000000u) : ~u;
  return __uint_as_float(u);
}

// ---------------- copy input x (B,3,N) -> H rows [0,3) ----------------
__global__ void k_convert(const float* __restrict__ x, float* __restrict__ H){
  int i = blockIdx.x*256 + threadIdx.x;
  if (i >= BATCH*3*NPTS) return;
  int b = i / (3*NPTS); int r = i % (3*NPTS);
  H[(size_t)b*HSTRIDE + r] = x[i];
}

// ---------------- per-point squared norms (+ zero SUM/SUMSQ for this layer) ----------------
__global__ void k_norms(const float* __restrict__ X, int C, float* __restrict__ X2,
                        float* __restrict__ SUMZ){
  int i = blockIdx.x*256 + threadIdx.x;     // b*2048+n
  if (i < 1024) SUMZ[i] = 0.f;              // SUM[512] ++ SUMSQ[512] contiguous
  int b = i >> 11, n = i & 2047;
  const float* Xb = X + (size_t)b*HSTRIDE + n;
  float s = 0.f;
  for (int c=0;c<C;++c){ float v = Xb[(size_t)c*NPTS]; s = fmaf(v,v,s); }
  X2[i] = s;
}

// ---------------- X (b,c,n) fp32 -> Xhi/Xlo (b,n,Cpad) f16 split ----------------
__global__ __launch_bounds__(256) void k_xsplit(const float* __restrict__ X, int C, int Cpad,
        _Float16* __restrict__ Xhi, _Float16* __restrict__ Xlo)
{
  __shared__ float t[64][65];
  int b = blockIdx.z;
  int n0 = blockIdx.x*64, c0 = blockIdx.y*64;
  int tid = threadIdx.x; int l = tid & 63, m = tid >> 6;
  for (int cc = m; cc < 64; cc += 4){
    int c = c0 + cc;
    t[cc][l] = (c < C) ? X[(size_t)b*HSTRIDE + (size_t)c*NPTS + n0 + l] : 0.f;
  }
  __syncthreads();
  for (int nn = m; nn < 64; nn += 4){
    int c = c0 + l;
    if (c < Cpad){
      float v = t[l][nn];
      _Float16 h = (_Float16)v;
      size_t o = ((size_t)(b<<11)+n0+nn)*Cpad + c;
      Xhi[o] = h;
      Xlo[o] = (_Float16)(v - (float)h);
    }
  }
}

// ---------------- Gram via MFMA: G[n][m] = sum_c X[n][c]*X[m][c] ----------------
// 128x128 tile, 4 waves x (64x64); 3 MFMAs (hh,hl,lh) per fragment pair.
__global__ __launch_bounds__(256) void k_gram(const _Float16* __restrict__ Xhi,
        const _Float16* __restrict__ Xlo, int Cpad, int bbase,
        float* __restrict__ G0, float* __restrict__ G1)
{
  __shared__ half8 AsH[128][4]; __shared__ half8 AsL[128][4];
  __shared__ half8 BsH[128][4]; __shared__ half8 BsL[128][4];
  int bl = blockIdx.z;
  int b  = bbase + bl;
  float* G = bl ? G1 : G0;
  const _Float16* Hb = Xhi + (size_t)(b<<11)*Cpad;
  const _Float16* Lb = Xlo + (size_t)(b<<11)*Cpad;
  int m0 = blockIdx.x*128, n0 = blockIdx.y*128;
  int tid = threadIdx.x;
  int w = tid>>6, lane = tid&63;
  int wm = w>>1, wn = w&1;
  int quad = lane>>4, col = lane&15;
  f32x4 acc[4][4];
  #pragma unroll
  for (int i=0;i<4;++i)
    #pragma unroll
    for (int j=0;j<4;++j) acc[i][j] = (f32x4){0.f,0.f,0.f,0.f};

  for (int k0=0; k0<Cpad; k0+=32){
    #pragma unroll
    for (int h=0; h<2; ++h){
      int cid = tid + h*256;
      int row = cid>>2, kc = cid&3;
      size_t ao = (size_t)(n0+row)*Cpad + k0 + kc*8;
      size_t bo = (size_t)(m0+row)*Cpad + k0 + kc*8;
      AsH[row][kc] = *(const half8*)(Hb + ao);
      AsL[row][kc] = *(const half8*)(Lb + ao);
      BsH[row][kc] = *(const half8*)(Hb + bo);
      BsL[row][kc] = *(const half8*)(Lb + bo);
    }
    __syncthreads();
    half8 ah[4], al[4], bh[4], blo[4];
    #pragma unroll
    for (int mt=0;mt<4;++mt){ ah[mt] = AsH[wm*64 + mt*16 + col][quad];
                              al[mt] = AsL[wm*64 + mt*16 + col][quad]; }
    #pragma unroll
    for (int nt=0;nt<4;++nt){ bh[nt] = BsH[wn*64 + nt*16 + col][quad];
                              blo[nt] = BsL[wn*64 + nt*16 + col][quad]; }
    #pragma unroll
    for (int mt=0;mt<4;++mt)
      #pragma unroll
      for (int nt=0;nt<4;++nt){
        acc[mt][nt] = __builtin_amdgcn_mfma_f32_16x16x32_f16(ah[mt], bh[nt], acc[mt][nt], 0, 0, 0);
        acc[mt][nt] = __builtin_amdgcn_mfma_f32_16x16x32_f16(ah[mt], blo[nt], acc[mt][nt], 0, 0, 0);
        acc[mt][nt] = __builtin_amdgcn_mfma_f32_16x16x32_f16(al[mt], bh[nt], acc[mt][nt], 0, 0, 0);
      }
    __syncthreads();
  }
  // C/D layout: col(m within 16)=lane&15, row(n within 16)=quad*4+r
  #pragma unroll
  for (int mt=0;mt<4;++mt){
    #pragma unroll
    for (int r=0;r<4;++r){
      int n = n0 + wm*64 + mt*16 + quad*4 + r;
      #pragma unroll
      for (int nt=0;nt<4;++nt){
        int m = m0 + wn*64 + nt*16 + col;
        G[(size_t)n*2048 + m] = acc[mt][nt][r];
      }
    }
  }
}

// ---------------- top-20 selection from Gram row ----------------
// 32 register slots per lane: slot (ch,cp) <-> candidate m = ch*256 + (lane<<2) + cp
#define KNN_CH(OPC) OPC(0) OPC(1) OPC(2) OPC(3) OPC(4) OPC(5) OPC(6) OPC(7)
#define DECL_CH(ch) float d##ch##_0,d##ch##_1,d##ch##_2,d##ch##_3;
#define LOADG_CH(ch) { float4 g = *(const float4*)(grow + (ch)*256 + base); \
  float4 xm = *(const float4*)(x2b + (ch)*256 + base); \
  d##ch##_0 = x2n + xm.x - 2.f*g.x; d##ch##_1 = x2n + xm.y - 2.f*g.y; \
  d##ch##_2 = x2n + xm.z - 2.f*g.z; d##ch##_3 = x2n + xm.w - 2.f*g.w; }
#define DECL_G(ch) float gv##ch; int gm##ch;
// strict < in ascending slot order -> smallest idx among exact ties
#define MKCH(ch) { gv##ch = d##ch##_0; gm##ch = (ch)*256 + base; \
  if (d##ch##_1 < gv##ch){ gv##ch = d##ch##_1; gm##ch = (ch)*256 + base + 1; } \
  if (d##ch##_2 < gv##ch){ gv##ch = d##ch##_2; gm##ch = (ch)*256 + base + 2; } \
  if (d##ch##_3 < gv##ch){ gv##ch = d##ch##_3; gm##ch = (ch)*256 + base + 3; } }
#define REMCASE(ch) case ch: { \
  if (own){ if (cp==0) d##ch##_0 = FLT_MAX; else if (cp==1) d##ch##_1 = FLT_MAX; \
            else if (cp==2) d##ch##_2 = FLT_MAX; else d##ch##_3 = FLT_MAX; } \
  MKCH(ch) } break;

__global__ __launch_bounds__(256,4) void k_sel(const float* __restrict__ G0,
        const float* __restrict__ G1, const float* __restrict__ X2,
        int bbase, int* __restrict__ IDX)
{
  int tid = threadIdx.x;
  int w = tid >> 6, lane = tid & 63;
  int n = blockIdx.x*4 + w;
  int b = bbase + blockIdx.y;
  const float* grow = (blockIdx.y ? G1 : G0) + (size_t)n*2048;
  const float* x2b  = X2 + (b<<11);
  float x2n = x2b[n];
  int base = lane << 2;
  KNN_CH(DECL_CH)
  KNN_CH(LOADG_CH)
  KNN_CH(DECL_G)
  KNN_CH(MKCH)
  int* op = IDX + ((size_t)(b<<11)+n)*KNN;
  for (int it=0; it<KNN; ++it){
    float v = fminf(fminf(fminf(gv0,gv1),fminf(gv2,gv3)),
                    fminf(fminf(gv4,gv5),fminf(gv6,gv7)));
    #pragma unroll
    for (int s=1; s<64; s<<=1) v = fminf(v, __shfl_xor(v, s));
    int mc = 0x7fffffff;
    mc = (gv7==v) ? gm7 : mc;
    mc = (gv6==v) ? gm6 : mc;
    mc = (gv5==v) ? gm5 : mc;
    mc = (gv4==v) ? gm4 : mc;
    mc = (gv3==v) ? gm3 : mc;
    mc = (gv2==v) ? gm2 : mc;
    mc = (gv1==v) ? gm1 : mc;
    mc = (gv0==v) ? gm0 : mc;
    int m = mc;
    #pragma unroll
    for (int s=1; s<64; s<<=1) m = min(m, __shfl_xor(m, s));
    if (lane==0) op[it] = m;
    int sm = __builtin_amdgcn_readfirstlane(m);
    bool own = (lane == ((sm>>2)&63));
    int cp = sm & 3;
    switch (sm >> 8){ KNN_CH(REMCASE) }
  }
}

// ---------------- v = Wd*x, u = (Wc-Wd)*x : 128x64 tile, 8x4/thread ----------------
__global__ __launch_bounds__(256) void k_vu(const float* __restrict__ X,
        const float* __restrict__ W, int C, int O,
        float* __restrict__ V, float* __restrict__ U)
{
  __shared__ float Xs[8][128];
  __shared__ float Wdv[8][64];
  __shared__ float Wuv[8][64];
  int b = blockIdx.z, n0 = blockIdx.x*128, o0 = blockIdx.y*64;
  int tid = threadIdx.x;
  int tj = tid & 15, ti = tid >> 4;   // tj -> o (4 each), ti -> n (8 each)
  float4 aV[8], aU[8];
  #pragma unroll
  for (int i=0;i<8;++i){ aV[i]=make_float4(0,0,0,0); aU[i]=make_float4(0,0,0,0); }
  const float* Xb = X + (size_t)b*HSTRIDE;
  for (int c0=0;c0<C;c0+=8){
    {
      int cc = tid >> 5, nn = (tid & 31) * 4; int c = c0 + cc;
      float4 v = (c<C) ? *(const float4*)(Xb + (size_t)c*NPTS + n0 + nn)
                       : make_float4(0,0,0,0);
      *(float4*)&Xs[cc][nn] = v;
    }
    for (int l=tid;l<512;l+=256){
      int oo=l>>3, cc=l&7, c=c0+cc;
      float wd=0.f, wu=0.f;
      if (c<C){
        const float* wr = W + (size_t)(o0+oo)*(2*C);
        wd = wr[c]; wu = wr[C+c] - wd;
      }
      Wdv[cc][oo]=wd; Wuv[cc][oo]=wu;
    }
    __syncthreads();
    #pragma unroll
    for (int cc=0;cc<8;++cc){
      float4 x0 = *(float4*)&Xs[cc][ti*8];
      float4 x1 = *(float4*)&Xs[cc][ti*8+4];
      float4 wd = *(float4*)&Wdv[cc][tj*4];
      float4 wu = *(float4*)&Wuv[cc][tj*4];
      float xs[8] = {x0.x,x0.y,x0.z,x0.w,x1.x,x1.y,x1.z,x1.w};
      #pragma unroll
      for (int i=0;i<8;++i){
        aV[i].x = fmaf(xs[i], wd.x, aV[i].x);
        aV[i].y = fmaf(xs[i], wd.y, aV[i].y);
        aV[i].z = fmaf(xs[i], wd.z, aV[i].z);
        aV[i].w = fmaf(xs[i], wd.w, aV[i].w);
        aU[i].x = fmaf(xs[i], wu.x, aU[i].x);
        aU[i].y = fmaf(xs[i], wu.y, aU[i].y);
        aU[i].z = fmaf(xs[i], wu.z, aU[i].z);
        aU[i].w = fmaf(xs[i], wu.w, aU[i].w);
      }
    }
    __syncthreads();
  }
  #pragma unroll
  for (int i=0;i<8;++i){
    int n = n0 + ti*8 + i;
    size_t basep = ((size_t)b*NPTS + n)*O + o0 + tj*4;
    *(float4*)(V+basep) = aV[i];
    *(float4*)(U+basep) = aU[i];
  }
}

// ---------------- single gather pass: ymax/ymin per (b,n,o) + channel sum/sumsq ----------------
__global__ __launch_bounds__(256) void k_gather(const float* __restrict__ V, const float* __restrict__ U,
        const int* __restrict__ IDX, int O,
        float* __restrict__ YMX, float* __restrict__ YMN,
        float* __restrict__ SUM, float* __restrict__ SUMSQ)
{
  const int NT = 8;
  __shared__ int sidx[NT*KNN];
  int bi = blockIdx.x;                 // 4*256 blocks
  int b  = bi >> 8;
  int n0 = (bi & 255) * NT;
  int tid = threadIdx.x;
  for (int l = tid; l < NT*KNN; l += 256)
    sidx[l] = IDX[((size_t)(b<<11)+n0)*KNN + l];
  __syncthreads();
  int othr  = (O < 256) ? O : 256;     // power of 2
  int o0    = tid & (othr-1);
  int ns    = tid / othr;
  int nstep = 256 / othr;
  for (int o = o0; o < O; o += othr){
    float s = 0.f, q = 0.f;
    for (int nn = ns; nn < NT; nn += nstep){
      int n = n0 + nn;
      size_t ub = ((size_t)(b<<11)+n)*O + o;
      float u = U[ub];
      float mx = -FLT_MAX, mn = FLT_MAX;
      #pragma unroll
      for (int k=0;k<KNN;++k){
        int m = sidx[nn*KNN+k];
        float y = V[((size_t)(b<<11)+m)*O + o] + u;
        mx = fmaxf(mx,y); mn = fminf(mn,y);
        s += y; q = fmaf(y,y,q);
      }
      YMX[ub] = mx; YMN[ub] = mn;
    }
    atomicAdd(&SUM[o], s); atomicAdd(&SUMSQ[o], q);
  }
}

__global__ void k_finalize(const float* __restrict__ SUM, const float* __restrict__ SUMSQ,
        const float* __restrict__ g, const float* __restrict__ bt,
        int O, float invM, float* __restrict__ SC, float* __restrict__ SH){
  int o = blockIdx.x*256 + threadIdx.x;
  if (o>=O) return;
  float m = SUM[o]*invM;
  float var = SUMSQ[o]*invM - m*m;
  float sc = g[o] * rsqrtf(var + 1e-5f);
  SC[o]=sc; SH[o] = bt[o] - m*sc;
}

// ---------------- apply BN + lrelu to recorded extrema; transpose (b,n,o)->(b,o,n) ----------------
__global__ __launch_bounds__(256) void k_apply(const float* __restrict__ YMX, const float* __restrict__ YMN,
        const float* __restrict__ SC, const float* __restrict__ SH,
        int O, float* __restrict__ OUT)
{
  __shared__ float t[64][65];
  int b = blockIdx.z;
  int o0 = blockIdx.y*64, n0 = blockIdx.x*64;
  int tid = threadIdx.x;
  int lo = tid & 63, ln = tid >> 6;
  float sc = SC[o0+lo], sh = SH[o0+lo];
  for (int nn = ln; nn < 64; nn += 4){
    size_t idx = ((size_t)(b<<11)+n0+nn)*O + o0 + lo;
    float v = (sc >= 0.f) ? YMX[idx] : YMN[idx];
    float y = fmaf(sc, v, sh);
    y = (y > 0.f) ? y : 0.2f*y;
    t[lo][nn] = y;
  }
  __syncthreads();
  for (int oo = ln; oo < 64; oo += 4){
    OUT[(size_t)b*HSTRIDE + (size_t)(o0+oo)*NPTS + n0 + lo] = t[oo][lo];
  }
}

// ---------------- transpose H (b,c,n) fp32 -> Hf16 (b,n,KPAD) f16, zero-pad c>=963 ----------------
__global__ __launch_bounds__(256) void k_h2f16(const float* __restrict__ H, _Float16* __restrict__ Hf){
  __shared__ float t[64][65];
  int b = blockIdx.z;
  int n0 = blockIdx.x*64, c0 = blockIdx.y*64;
  int tid = threadIdx.x; int l = tid & 63, m = tid >> 6;
  for (int cc = m; cc < 64; cc += 4){
    int c = c0 + cc;
    t[cc][l] = (c < CH_H) ? H[(size_t)b*HSTRIDE + (size_t)c*NPTS + n0 + l] : 0.f;
  }
  __syncthreads();
  for (int nn = m; nn < 64; nn += 4){
    int c = c0 + l;
    if (c < KPAD)
      Hf[((size_t)(b<<11)+n0+nn)*KPAD + c] = (_Float16)t[l][nn];
  }
}

// ---------------- w5 -> f16 (+ zero l5 reduction buffers) ----------------
__global__ void k_w5f16(const float* __restrict__ w5, _Float16* __restrict__ Wf,
                        unsigned* __restrict__ z){
  int i = blockIdx.x*256 + threadIdx.x;
  if (i < 12288) z[i] = 0u;                 // SUM5,SUMSQ5,MAXB
  else if (i < 20480) z[i] = 0xFFFFFFFFu;   // MINB
  if (i >= 2048*KPAD) return;
  int o = i / KPAD, c = i - o*KPAD;
  Wf[i] = (c < CH_H) ? (_Float16)w5[(size_t)o*CH_H + c] : (_Float16)0.f;
}

// ---------------- layer-5 GEMM on MFMA, fused BN-stat/max epilogue ----------------
__global__ __launch_bounds__(256) void k_l5mfma(const _Float16* __restrict__ Wf,
        const _Float16* __restrict__ Hf,
        float* __restrict__ SUM5, float* __restrict__ SUMSQ5,
        unsigned* __restrict__ MAXB, unsigned* __restrict__ MINB)
{
  __shared__ half8 As[128][4];   // [o_row][k-chunk of 8]
  __shared__ half8 Bs[128][4];   // [n_row][k-chunk of 8]
  int b  = blockIdx.z;
  int n0 = blockIdx.x*128, o0 = blockIdx.y*128;
  int tid = threadIdx.x;
  int w = tid>>6, lane = tid&63;
  int wm = w>>1, wn = w&1;          // wave grid 2x2
  int quad = lane>>4, col = lane&15;
  f32x4 acc[4][4];
  #pragma unroll
  for (int i=0;i<4;++i)
    #pragma unroll
    for (int j=0;j<4;++j) acc[i][j] = (f32x4){0.f,0.f,0.f,0.f};

  for (int k0=0; k0<KPAD; k0+=32){
    #pragma unroll
    for (int h=0; h<2; ++h){
      int cid = tid + h*256;
      int row = cid>>2, kc = cid&3;
      As[row][kc] = *(const half8*)(Wf + (size_t)(o0+row)*KPAD + k0 + kc*8);
      Bs[row][kc] = *(const half8*)(Hf + ((size_t)(b<<11)+n0+row)*KPAD + k0 + kc*8);
    }
    __syncthreads();
    half8 af[4], bf[4];
    #pragma unroll
    for (int mt=0;mt<4;++mt) af[mt] = As[wm*64 + mt*16 + col][quad];
    #pragma unroll
    for (int nt=0;nt<4;++nt) bf[nt] = Bs[wn*64 + nt*16 + col][quad];
    #pragma unroll
    for (int mt=0;mt<4;++mt)
      #pragma unroll
      for (int nt=0;nt<4;++nt)
        acc[mt][nt] = __builtin_amdgcn_mfma_f32_16x16x32_f16(af[mt], bf[nt], acc[mt][nt], 0, 0, 0);
    __syncthreads();
  }
  // epilogue: C/D layout col(n)=lane&15, row(o)=quad*4+reg
  #pragma unroll
  for (int mt=0;mt<4;++mt){
    #pragma unroll
    for (int r=0;r<4;++r){
      float s=0.f, q=0.f, mx=-FLT_MAX, mn=FLT_MAX;
      #pragma unroll
      for (int nt=0;nt<4;++nt){
        float y = acc[mt][nt][r];
        s += y; q = fmaf(y,y,q);
        mx = fmaxf(mx,y); mn = fminf(mn,y);
      }
      #pragma unroll
      for (int d=8; d; d>>=1){
        s += __shfl_down(s,(unsigned)d,16);
        q += __shfl_down(q,(unsigned)d,16);
        mx = fmaxf(mx,__shfl_down(mx,(unsigned)d,16));
        mn = fminf(mn,__shfl_down(mn,(unsigned)d,16));
      }
      if (col==0){
        int o = o0 + wm*64 + mt*16 + quad*4 + r;
        atomicAdd(&SUM5[o], s);
        atomicAdd(&SUMSQ5[o], q);
        atomicMax(&MAXB[(b<<11)+o], fenc(mx));
        atomicMin(&MINB[(b<<11)+o], fenc(mn));
      }
    }
  }
}

// ---------------- layer-5 finalize: BN + leaky_relu + max over n -> P (B,2048) ----------------
__global__ void k_l5_final(const float* __restrict__ SUM5, const float* __restrict__ SUMSQ5,
        const unsigned* __restrict__ MAXB, const unsigned* __restrict__ MINB,
        const float* __restrict__ g5, const float* __restrict__ b5, float* __restrict__ P)
{
  int o = blockIdx.x*256 + threadIdx.x;
  if (o>=2048) return;
  float m = SUM5[o]*(1.f/8192.f);
  float var = SUMSQ5[o]*(1.f/8192.f) - m*m;
  float sc = g5[o] * rsqrtf(var + 1e-5f);
  float sh = b5[o] - m*sc;
  for (int b=0;b<4;++b){
    float mx = fdec(MAXB[b*2048+o]);
    float mn = fdec(MINB[b*2048+o]);
    float v = (sc >= 0.f) ? fmaf(sc,mx,sh) : fmaf(sc,mn,sh);
    v = (v > 0.f) ? v : 0.2f*v;
    P[b*2048 + o] = v;
  }
}

// ---------------- small FC: Y(B,O) = W(O,Cin)*Z(B,Cin) + bias, one wave per o ----------------
__global__ __launch_bounds__(256) void k_fc(const float* __restrict__ W, const float* __restrict__ bias,
        const float* __restrict__ Z, int Cin, int O, float* __restrict__ Y)
{
  int o = blockIdx.x*4 + (threadIdx.x>>6);
  int lane = threadIdx.x & 63;
  if (o >= O) return;
  const float* wr = W + (size_t)o*Cin;
  float a0=0.f,a1=0.f,a2=0.f,a3=0.f;
  for (int c=lane;c<Cin;c+=64){
    float w = wr[c];
    a0 = fmaf(w, Z[c],        a0);
    a1 = fmaf(w, Z[Cin+c],    a1);
    a2 = fmaf(w, Z[2*Cin+c],  a2);
    a3 = fmaf(w, Z[3*Cin+c],  a3);
  }
  #pragma unroll
  for (int s=32;s;s>>=1){
    a0 += __shfl_down(a0,(unsigned)s); a1 += __shfl_down(a1,(unsigned)s);
    a2 += __shfl_down(a2,(unsigned)s); a3 += __shfl_down(a3,(unsigned)s);
  }
  if (lane==0){
    float bb = bias[o];
    Y[o]=a0+bb; Y[O+o]=a1+bb; Y[2*O+o]=a2+bb; Y[3*O+o]=a3+bb;
  }
}

// ---------------- BN over batch (4 samples) + relu ----------------
__global__ void k_bn4(const float* __restrict__ Y, const float* __restrict__ g, const float* __restrict__ bt,
                      int O, float* __restrict__ Z, int zstride, int zoff)
{
  int o = blockIdx.x*256 + threadIdx.x;
  if (o>=O) return;
  float v0=Y[o], v1=Y[O+o], v2=Y[2*O+o], v3=Y[3*O+o];
  float m = 0.25f*(v0+v1+v2+v3);
  float d0=v0-m, d1=v1-m, d2=v2-m, d3=v3-m;
  float var = 0.25f*(d0*d0+d1*d1+d2*d2+d3*d3);
  float sc = g[o] * rsqrtf(var + 1e-5f);
  float sh = bt[o] - m*sc;
  Z[0*zstride+zoff+o] = fmaxf(fmaf(sc,v0,sh), 0.f);
  Z[1*zstride+zoff+o] = fmaxf(fmaf(sc,v1,sh), 0.f);
  Z[2*zstride+zoff+o] = fmaxf(fmaf(sc,v2,sh), 0.f);
  Z[3*zstride+zoff+o] = fmaxf(fmaf(sc,v3,sh), 0.f);
}

__global__ void k_copy_p(const float* __restrict__ P, float* __restrict__ Z){
  int i = blockIdx.x*256 + threadIdx.x;   // < 4*2048
  int b = i>>11, o = i&2047;
  Z[b*4096 + 2048 + o] = P[i];
}

// ---------------- final: y8 = w8*z7 + wb8, tanh, fp32 out (4,400) ----------------
__global__ __launch_bounds__(256) void k_final(const float* __restrict__ W8, const float* __restrict__ wb8,
        const float* __restrict__ Z7, float* __restrict__ out)
{
  int o = blockIdx.x*4 + (threadIdx.x>>6);
  int lane = threadIdx.x & 63;
  if (o >= 400) return;
  const float* wr = W8 + (size_t)o*4096;
  float a0=0.f,a1=0.f,a2=0.f,a3=0.f;
  for (int c=lane;c<4096;c+=64){
    float w = wr[c];
    a0 = fmaf(w, Z7[c],        a0);
    a1 = fmaf(w, Z7[4096+c],   a1);
    a2 = fmaf(w, Z7[2*4096+c], a2);
    a3 = fmaf(w, Z7[3*4096+c], a3);
  }
  #pragma unroll
  for (int s=32;s;s>>=1){
    a0 += __shfl_down(a0,(unsigned)s); a1 += __shfl_down(a1,(unsigned)s);
    a2 += __shfl_down(a2,(unsigned)s); a3 += __shfl_down(a3,(unsigned)s);
  }
  if (lane==0){
    float bb = wb8[o];
    out[0*400+o] = tanhf(a0+bb);
    out[1*400+o] = tanhf(a1+bb);
    out[2*400+o] = tanhf(a2+bb);
    out[3*400+o] = tanhf(a3+bb);
  }
}

extern "C" void kernel_launch(void* const* d_in, const int* in_sizes, int n_in,
                              void* d_out, int out_size, void* d_ws, size_t ws_size,
                              hipStream_t stream)
{
  const float* x   = (const float*)d_in[0];
  const float* w_e[4]  = {(const float*)d_in[1], (const float*)d_in[4], (const float*)d_in[7], (const float*)d_in[10]};
  const float* g_e[4]  = {(const float*)d_in[2], (const float*)d_in[5], (const float*)d_in[8], (const float*)d_in[11]};
  const float* b_e[4]  = {(const float*)d_in[3], (const float*)d_in[6], (const float*)d_in[9], (const float*)d_in[12]};
  const float* w5  = (const float*)d_in[13];
  const float* g5  = (const float*)d_in[14];
  const float* b5  = (const float*)d_in[15];
  const float* w6  = (const float*)d_in[16];
  const float* wb6 = (const float*)d_in[17];
  const float* g6  = (const float*)d_in[18];
  const float* b6  = (const float*)d_in[19];
  const float* w7  = (const float*)d_in[20];
  const float* wb7 = (const float*)d_in[21];
  const float* g7  = (const float*)d_in[22];
  const float* b7  = (const float*)d_in[23];
  const float* w8  = (const float*)d_in[24];
  const float* wb8 = (const float*)d_in[25];

  float* WS = (float*)d_ws;
  float* H    = WS;                          // 7,888,896
  float* V    = WS + 7888896;                // 4,194,304
  float* U    = V  + 4194304;                // 4,194,304
  float* YMX  = U  + 4194304;                // 4,194,304
  float* YMN  = YMX+ 4194304;                // 4,194,304
  int*   IDX  = (int*)(YMN + 4194304);       //   163,840 ints
  float* X2   = (float*)(IDX + 163840);      //     8,192
  float* SUM  = X2 + 8192;                   //       512
  float* SUMSQ= SUM + 512;                   //       512
  float* SC   = SUMSQ + 512;                 //       512
  float* SH   = SC + 512;                    //       512
  float* SUM5 = SH + 512;                    //     2,048
  float* SUMSQ5 = SUM5 + 2048;               //     2,048
  unsigned* MAXB = (unsigned*)(SUMSQ5 + 2048); //   8,192
  unsigned* MINB = MAXB + 8192;              //     8,192
  float* P    = (float*)(MINB + 8192);       //     8,192
  float* Y6   = P + 8192;                    //     8,192
  float* Z    = Y6 + 8192;                   //    16,384
  float* Y7   = Z + 16384;                   //    16,384
  float* Z7   = Y7 + 16384;                  //    16,384
  // aliases (stage-disjoint lifetimes):
  _Float16* Hf  = (_Float16*)V;              // l5 operand, after edge stages
  _Float16* Wf  = (_Float16*)U;              // l5 operand
  _Float16* Xhi = (_Float16*)U;              // knn split, dead before k_vu writes U
  _Float16* Xlo = (_Float16*)U + 4*2048*256; // 4 MB + 4 MB <= U (16.8 MB)
  float* G0 = YMX;                           // per-batch Gram (16.8 MB each)
  float* G1 = YMN;

  k_convert<<<96,256,0,stream>>>(x, H);

  const int Cin_[4]  = {3,64,128,256};
  const int Cpad_[4] = {32,64,128,256};
  const int O_[4]    = {64,128,256,512};
  const int ioff_[4] = {0,3,67,195};
  const int ooff_[4] = {3,67,195,451};

  for (int l=0;l<4;++l){
    const float* Xl = H + (size_t)ioff_[l]*NPTS;
    int C = Cin_[l], Cpad = Cpad_[l], O = O_[l];
    k_norms<<<32,256,0,stream>>>(Xl, C, X2, SUM);
    dim3 gxs(32, (Cpad+63)/64, 4);
    k_xsplit<<<gxs,256,0,stream>>>(Xl, C, Cpad, Xhi, Xlo);
    dim3 ggr(16,16,2);
    k_gram<<<ggr,256,0,stream>>>(Xhi, Xlo, Cpad, 0, G0, G1);
    dim3 gsl(512,2);
    k_sel<<<gsl,256,0,stream>>>(G0, G1, X2, 0, IDX);
    k_gram<<<ggr,256,0,stream>>>(Xhi, Xlo, Cpad, 2, G0, G1);
    k_sel<<<gsl,256,0,stream>>>(G0, G1, X2, 2, IDX);
    dim3 gvu(16, O/64, 4);
    k_vu<<<gvu,256,0,stream>>>(Xl, w_e[l], C, O, V, U);
    k_gather<<<1024,256,0,stream>>>(V, U, IDX, O, YMX, YMN, SUM, SUMSQ);
    k_finalize<<<2,256,0,stream>>>(SUM, SUMSQ, g_e[l], b_e[l], O, 1.f/163840.f, SC, SH);
    dim3 gap(32, O/64, 4);
    k_apply<<<gap,256,0,stream>>>(YMX, YMN, SC, SH, O, H + (size_t)ooff_[l]*NPTS);
  }

  // ---- layer 5 on MFMA ----
  dim3 gtr(32,16,4);
  k_h2f16<<<gtr,256,0,stream>>>(H, Hf);
  k_w5f16<<<(2048*KPAD+255)/256,256,0,stream>>>(w5, Wf, (unsigned*)SUM5);
  dim3 g5g(16,16,4);
  k_l5mfma<<<g5g,256,0,stream>>>(Wf, Hf, SUM5, SUMSQ5, MAXB, MINB);
  k_l5_final<<<8,256,0,stream>>>(SUM5, SUMSQ5, MAXB, MINB, g5, b5, P);

  k_fc<<<512,256,0,stream>>>(w6, wb6, P, 2048, 2048, Y6);
  k_bn4<<<8,256,0,stream>>>(Y6, g6, b6, 2048, Z, 4096, 0);
  k_copy_p<<<32,256,0,stream>>>(P, Z);
  k_fc<<<1024,256,0,stream>>>(w7, wb7, Z, 4096, 4096, Y7);
  k_bn4<<<16,256,0,stream>>>(Y7, g7, b7, 4096, Z7, 4096, 0);
  k_final<<<100,256,0,stream>>>(w8, wb8, Z7, (float*)d_out);
}